// Round 5
// baseline (1165.490 us; speedup 1.0000x reference)
//
#include <hip/hip_runtime.h>
#include <hip/hip_bf16.h>
#include <cstdint>
#include <cstddef>

typedef unsigned long long u64;
typedef unsigned int u32;
typedef unsigned short ushort_t;

typedef __attribute__((ext_vector_type(8))) short short8;
typedef __attribute__((ext_vector_type(4))) float f32x4;

#define MARGIN_TAU 7.5e-4   // 6 sigma of bf16-y direction noise on score margins

// ---------------- utilities ----------------
__device__ __forceinline__ u64 shfl_xor_u64(u64 v, int m) {
    u32 lo = (u32)v;
    u32 hi = (u32)(v >> 32);
    lo = __shfl_xor(lo, m, 64);
    hi = __shfl_xor(hi, m, 64);
    return ((u64)hi << 32) | lo;
}

__device__ __forceinline__ ushort_t f2bf(float f) {
    u32 u = __float_as_uint(f);
    u32 r = (u + 0x7fffu + ((u >> 16) & 1u)) >> 16;
    return (ushort_t)r;
}

__device__ __forceinline__ float bf2f(ushort_t h) {
    return __uint_as_float(((u32)h) << 16);
}

// merge sorted pair (m1<=m2) with sorted pair (o1<=o2) -> top-2 smallest
__device__ __forceinline__ void merge_pair(u64& m1, u64& m2, u64 o1, u64 o2) {
    u64 lo = m1 < o1 ? m1 : o1;
    u64 hi = m1 < o1 ? o1 : m1;
    u64 x  = m2 < o2 ? m2 : o2;
    m1 = lo;
    m2 = hi < x ? hi : x;
}

// sorted-insert key k into ascending top-4
__device__ __forceinline__ void ins4(u64& t0, u64& t1, u64& t2, u64& t3, u64 k) {
    bool c0 = k < t0, c1 = k < t1, c2 = k < t2, c3 = k < t3;
    t3 = c3 ? (c2 ? t2 : k) : t3;
    t2 = c2 ? (c1 ? t1 : k) : t2;
    t1 = c1 ? (c0 ? t0 : k) : t1;
    t0 = c0 ? k : t0;
}

// full-wave butterfly: each lane holds sorted (t0..t3); converges to global top-4
__device__ __forceinline__ void butterfly4(u64& t0, u64& t1, u64& t2, u64& t3) {
    #pragma unroll
    for (int mk = 1; mk < 64; mk <<= 1) {
        u64 o0 = shfl_xor_u64(t0, mk), o1 = shfl_xor_u64(t1, mk);
        u64 o2 = shfl_xor_u64(t2, mk), o3 = shfl_xor_u64(t3, mk);
        ins4(t0, t1, t2, t3, o0);
        ins4(t0, t1, t2, t3, o1);
        ins4(t0, t1, t2, t3, o2);
        ins4(t0, t1, t2, t3, o3);
    }
}

// sortable key from score (maximize score == minimize key), idx in low 32
__device__ __forceinline__ u64 score_key(float score, int col) {
    float f = -score;
    u32 fb = __float_as_uint(f);
    fb = (fb & 0x80000000u) ? ~fb : (fb | 0x80000000u);
    return ((u64)fb << 32) | (u32)col;
}

// ---------------- kernel 0: zero the worklist counter ----------------
__global__ void k_zero(u32* __restrict__ count) {
    if (threadIdx.x == 0) *count = 0;
}

// ---------------- kernel A: fp32 -> bf16 elementwise (8/thread) ----------------
__global__ void k_cvt8(const float* __restrict__ src, ushort_t* __restrict__ dst, int n8) {
    int i = blockIdx.x * blockDim.x + threadIdx.x;
    const int stride = gridDim.x * blockDim.x;
    for (; i < n8; i += stride) {
        float4 a = ((const float4*)src)[(size_t)i * 2];
        float4 b = ((const float4*)src)[(size_t)i * 2 + 1];
        short8 p;
        p[0] = (short)f2bf(a.x); p[1] = (short)f2bf(a.y);
        p[2] = (short)f2bf(a.z); p[3] = (short)f2bf(a.w);
        p[4] = (short)f2bf(b.x); p[5] = (short)f2bf(b.y);
        p[6] = (short)f2bf(b.z); p[7] = (short)f2bf(b.w);
        ((short8*)dst)[i] = p;
    }
}

// ---------------- kernel B: transpose P [k][n] -> PT [n][k], bf16 ----------------
__global__ __launch_bounds__(256) void k_trP(const float* __restrict__ P,
                                             ushort_t* __restrict__ PT) {
    __shared__ float t[64][65];
    const int tx = threadIdx.x & 63;
    const int ty = threadIdx.x >> 6;   // 0..3
    const int kb = blockIdx.x * 64;
    const int nb = blockIdx.y * 64;
    #pragma unroll
    for (int r = ty; r < 64; r += 4) t[r][tx] = P[(size_t)(kb + r) * 512 + nb + tx];
    __syncthreads();
    #pragma unroll
    for (int r = ty; r < 64; r += 4)
        PT[(size_t)(nb + r) * 512 + kb + tx] = f2bf(t[tx][r]);
}

// ---------------- kernel 1: normalize codebooks -> bf16, store fp64 ||c||^2 ----------------
__global__ void k_codes(const float* __restrict__ cb, ushort_t* __restrict__ cbf,
                        double* __restrict__ cnorm2) {
    const int row = blockIdx.x;
    const int t = threadIdx.x;  // 0..127
    const float* src = cb + (size_t)row * 512 + t * 4;
    float4 v = *(const float4*)src;
    double s = (double)v.x * v.x + (double)v.y * v.y + (double)v.z * v.z + (double)v.w * v.w;
    #pragma unroll
    for (int m = 1; m < 64; m <<= 1) s += __shfl_xor(s, m, 64);
    __shared__ double sw[2];
    if ((t & 63) == 0) sw[t >> 6] = s;
    __syncthreads();
    double tot = sw[0] + sw[1];
    double inv = 1.0 / fmax(sqrt(tot), 1e-12);
    ushort4 o;
    o.x = f2bf((float)((double)v.x * inv));
    o.y = f2bf((float)((double)v.y * inv));
    o.z = f2bf((float)((double)v.z * inv));
    o.w = f2bf((float)((double)v.w * inv));
    *(ushort4*)(cbf + (size_t)row * 512 + t * 4) = o;
    if (t == 0) cnorm2[row] = tot;
}

// ---------------- kernel 2: projection GEMM ybf = xbf @ PT^T via MFMA ----------------
// grid (256, 4). 128x128 tile, K=512 in 8 steps of 64. Both operands via
// global_load_lds (linear dest + pre-swizzled source; swizzle s' = s ^ (r&7)).
__global__ __launch_bounds__(256) void k_proj(const ushort_t* __restrict__ X,
                                              const ushort_t* __restrict__ PT,
                                              ushort_t* __restrict__ Ybf) {
    __shared__ ushort_t Ab[128 * 64];
    __shared__ ushort_t Bb[128 * 64];
    const int tid = threadIdx.x;
    const int lane = tid & 63;
    const int wid = tid >> 6;
    const int wm = wid & 1, wn = wid >> 1;
    const int rowBase = blockIdx.x * 128;
    const int colBase = blockIdx.y * 128;

    const ushort_t* asrc[4];
    const ushort_t* bsrc[4];
    int ldsoff[4];
    #pragma unroll
    for (int i = 0; i < 4; i++) {
        const int L = i * 256 + tid;
        const int r = L >> 3;
        const int s = (L & 7) ^ (r & 7);
        asrc[i] = X + (size_t)(rowBase + r) * 512 + s * 8;
        bsrc[i] = PT + (size_t)(colBase + r) * 512 + s * 8;
        ldsoff[i] = (i * 256 + (tid & ~63)) * 16;
    }

    f32x4 acc[4][4];
    #pragma unroll
    for (int i = 0; i < 4; i++)
        #pragma unroll
        for (int j = 0; j < 4; j++) {
            f32x4 z = {0.f, 0.f, 0.f, 0.f};
            acc[i][j] = z;
        }

    int aoff[4][2], boff[4][2];
    #pragma unroll
    for (int ti = 0; ti < 4; ti++)
        #pragma unroll
        for (int ks = 0; ks < 2; ks++) {
            const int sa = ks * 4 + (lane >> 4);
            const int ra = wm * 64 + ti * 16 + (lane & 15);
            aoff[ti][ks] = (ra * 8 + (sa ^ (ra & 7))) * 8;
            const int rb = wn * 64 + ti * 16 + (lane & 15);
            boff[ti][ks] = (rb * 8 + (sa ^ (rb & 7))) * 8;
        }

    for (int kt = 0; kt < 512; kt += 64) {
        #pragma unroll
        for (int i = 0; i < 4; i++) {
            __builtin_amdgcn_global_load_lds(
                (const __attribute__((address_space(1))) uint32_t*)(asrc[i] + kt),
                (__attribute__((address_space(3))) uint32_t*)((char*)Ab + ldsoff[i]), 16, 0, 0);
            __builtin_amdgcn_global_load_lds(
                (const __attribute__((address_space(1))) uint32_t*)(bsrc[i] + kt),
                (__attribute__((address_space(3))) uint32_t*)((char*)Bb + ldsoff[i]), 16, 0, 0);
        }
        __syncthreads();
        short8 af[4][2], bfr[4][2];
        #pragma unroll
        for (int ti = 0; ti < 4; ti++)
            #pragma unroll
            for (int ks = 0; ks < 2; ks++) {
                af[ti][ks]  = *(const short8*)(Ab + aoff[ti][ks]);
                bfr[ti][ks] = *(const short8*)(Bb + boff[ti][ks]);
            }
        #pragma unroll
        for (int ks = 0; ks < 2; ks++)
            #pragma unroll
            for (int ti = 0; ti < 4; ti++)
                #pragma unroll
                for (int tj = 0; tj < 4; tj++)
                    acc[ti][tj] = __builtin_amdgcn_mfma_f32_16x16x32_bf16(
                        af[ti][ks], bfr[tj][ks], acc[ti][tj], 0, 0, 0);
        __syncthreads();
    }

    // C/D layout: col = lane&15, row = (lane>>4)*4 + reg
    #pragma unroll
    for (int ti = 0; ti < 4; ti++)
        #pragma unroll
        for (int tj = 0; tj < 4; tj++) {
            const int col = colBase + wn * 64 + tj * 16 + (lane & 15);
            #pragma unroll
            for (int reg = 0; reg < 4; reg++) {
                const int row = rowBase + wm * 64 + ti * 16 + (lane >> 4) * 4 + reg;
                Ybf[(size_t)row * 512 + col] = f2bf(acc[ti][tj][reg]);
            }
        }
}

// ---------------- kernel 3: bf16 MFMA GEMM, fused per-row top-2 per 128-col block ----------------
// grid (256, 64). Both operands via global_load_lds. part2[row][64][2] u64 keys.
__global__ __launch_bounds__(256) void k_gemm(const ushort_t* __restrict__ Y,
                                              const ushort_t* __restrict__ C,
                                              u64* __restrict__ part2) {
    __shared__ ushort_t Ab[128 * 64];
    __shared__ ushort_t Bb[128 * 64];
    __shared__ u64 tmp[128][2][2];
    const int tid = threadIdx.x;
    const int lane = tid & 63;
    const int wid = tid >> 6;
    const int wm = wid & 1, wn = wid >> 1;
    const int rowBase = blockIdx.x * 128;
    const int colBase = blockIdx.y * 128;

    const ushort_t* asrc[4];
    const ushort_t* bsrc[4];
    int ldsoff[4];
    #pragma unroll
    for (int i = 0; i < 4; i++) {
        const int L = i * 256 + tid;
        const int r = L >> 3;
        const int s = (L & 7) ^ (r & 7);
        asrc[i] = Y + (size_t)(rowBase + r) * 512 + s * 8;
        bsrc[i] = C + (size_t)(colBase + r) * 512 + s * 8;
        ldsoff[i] = (i * 256 + (tid & ~63)) * 16;
    }

    f32x4 acc[4][4];
    #pragma unroll
    for (int i = 0; i < 4; i++)
        #pragma unroll
        for (int j = 0; j < 4; j++) {
            f32x4 z = {0.f, 0.f, 0.f, 0.f};
            acc[i][j] = z;
        }

    int aoff[4][2], boff[4][2];
    #pragma unroll
    for (int ti = 0; ti < 4; ti++)
        #pragma unroll
        for (int ks = 0; ks < 2; ks++) {
            const int sa = ks * 4 + (lane >> 4);
            const int ra = wm * 64 + ti * 16 + (lane & 15);
            aoff[ti][ks] = (ra * 8 + (sa ^ (ra & 7))) * 8;
            const int rb = wn * 64 + ti * 16 + (lane & 15);
            boff[ti][ks] = (rb * 8 + (sa ^ (rb & 7))) * 8;
        }

    for (int kt = 0; kt < 512; kt += 64) {
        #pragma unroll
        for (int i = 0; i < 4; i++) {
            __builtin_amdgcn_global_load_lds(
                (const __attribute__((address_space(1))) uint32_t*)(asrc[i] + kt),
                (__attribute__((address_space(3))) uint32_t*)((char*)Ab + ldsoff[i]), 16, 0, 0);
            __builtin_amdgcn_global_load_lds(
                (const __attribute__((address_space(1))) uint32_t*)(bsrc[i] + kt),
                (__attribute__((address_space(3))) uint32_t*)((char*)Bb + ldsoff[i]), 16, 0, 0);
        }
        __syncthreads();
        short8 af[4][2], bfr[4][2];
        #pragma unroll
        for (int ti = 0; ti < 4; ti++)
            #pragma unroll
            for (int ks = 0; ks < 2; ks++) {
                af[ti][ks]  = *(const short8*)(Ab + aoff[ti][ks]);
                bfr[ti][ks] = *(const short8*)(Bb + boff[ti][ks]);
            }
        #pragma unroll
        for (int ks = 0; ks < 2; ks++)
            #pragma unroll
            for (int ti = 0; ti < 4; ti++)
                #pragma unroll
                for (int tj = 0; tj < 4; tj++)
                    acc[ti][tj] = __builtin_amdgcn_mfma_f32_16x16x32_bf16(
                        af[ti][ks], bfr[tj][ks], acc[ti][tj], 0, 0, 0);
        __syncthreads();
    }

    // fused epilogue: per-row top-2 of this block's 128 cols
    #pragma unroll
    for (int ti = 0; ti < 4; ti++)
        #pragma unroll
        for (int reg = 0; reg < 4; reg++) {
            u64 m1 = ~0ull, m2 = ~0ull;
            #pragma unroll
            for (int tj = 0; tj < 4; tj++) {
                const int col = colBase + wn * 64 + tj * 16 + (lane & 15);
                u64 k = score_key(acc[ti][tj][reg], col);
                u64 hi = m1 > k ? m1 : k;
                m1 = m1 < k ? m1 : k;
                m2 = m2 < hi ? m2 : hi;
            }
            #pragma unroll
            for (int mk = 1; mk < 16; mk <<= 1) {
                u64 o1 = shfl_xor_u64(m1, mk);
                u64 o2 = shfl_xor_u64(m2, mk);
                merge_pair(m1, m2, o1, o2);
            }
            if ((lane & 15) == 0) {
                const int mrow = wm * 64 + ti * 16 + (lane >> 4) * 4 + reg;
                tmp[mrow][wn][0] = m1;
                tmp[mrow][wn][1] = m2;
            }
        }
    __syncthreads();
    if (tid < 128) {
        u64 r1 = tmp[tid][0][0], r2 = tmp[tid][0][1];
        merge_pair(r1, r2, tmp[tid][1][0], tmp[tid][1][1]);
        u64* dst = part2 + ((size_t)(rowBase + tid) * 64 + blockIdx.y) * 2;
        dst[0] = r1;
        dst[1] = r2;
    }
}

// ---------------- kernel 4: merge 128 keys -> top-8, fp64 rescore from ybf, flag near-ties ----------------
// grid 8192 x 256 (wave per row).
__global__ __launch_bounds__(256) void k_scorepick(const u64* __restrict__ part2,
                                                   const ushort_t* __restrict__ Ybf,
                                                   const float* __restrict__ cb,
                                                   const double* __restrict__ cnorm2,
                                                   const int* __restrict__ mask,
                                                   int* __restrict__ out,
                                                   u32* __restrict__ wl,
                                                   u32* __restrict__ count,
                                                   u32* __restrict__ cands8) {
    const int row = blockIdx.x * 4 + (threadIdx.x >> 6);
    const int lane = threadIdx.x & 63;

    const u64 k0 = part2[(size_t)row * 128 + lane];
    const u64 k1 = part2[(size_t)row * 128 + 64 + lane];

    // pass 1: global top-4
    u64 t0 = k0 < k1 ? k0 : k1;
    u64 t1 = k0 < k1 ? k1 : k0;
    u64 t2 = ~0ull, t3 = ~0ull;
    butterfly4(t0, t1, t2, t3);
    const u64 g0 = t0, g1 = t1, g2 = t2, g3 = t3;

    // pass 2: exclude top-4 (keys unique: col idx in low bits), get next-4
    u64 e0 = (k0 == g0 || k0 == g1 || k0 == g2 || k0 == g3) ? ~0ull : k0;
    u64 e1 = (k1 == g0 || k1 == g1 || k1 == g2 || k1 == g3) ? ~0ull : k1;
    u64 u0 = e0 < e1 ? e0 : e1;
    u64 u1 = e0 < e1 ? e1 : e0;
    u64 u2 = ~0ull, u3 = ~0ull;
    butterfly4(u0, u1, u2, u3);

    int vv[8];
    vv[0] = (int)(u32)(g0 & 0xffffffffu); vv[1] = (int)(u32)(g1 & 0xffffffffu);
    vv[2] = (int)(u32)(g2 & 0xffffffffu); vv[3] = (int)(u32)(g3 & 0xffffffffu);
    vv[4] = (int)(u32)(u0 & 0xffffffffu); vv[5] = (int)(u32)(u1 & 0xffffffffu);
    vv[6] = (int)(u32)(u2 & 0xffffffffu); vv[7] = (int)(u32)(u3 & 0xffffffffu);

    // fp64 rescore from bf16 y
    short8 yv = *(const short8*)(Ybf + (size_t)row * 512 + lane * 8);
    double yd[8];
    #pragma unroll
    for (int e = 0; e < 8; e++) yd[e] = (double)bf2f((ushort_t)yv[e]);
    double ss = 0.0;
    #pragma unroll
    for (int e = 0; e < 8; e++) ss = fma(yd[e], yd[e], ss);
    #pragma unroll
    for (int mk = 1; mk < 64; mk <<= 1) ss += __shfl_xor(ss, mk, 64);
    const double xinv = 1.0 / fmax(sqrt(ss), 1e-12);
    double xn[8];
    #pragma unroll
    for (int e = 0; e < 8; e++) xn[e] = yd[e] * xinv;

    double sc[8];
    #pragma unroll
    for (int c = 0; c < 8; c++) {
        const float* cr = cb + (size_t)vv[c] * 512 + lane * 8;
        float4 c0 = *(const float4*)cr;
        float4 c1 = *(const float4*)(cr + 4);
        double d = 0.0;
        d = fma(xn[0], (double)c0.x, d); d = fma(xn[1], (double)c0.y, d);
        d = fma(xn[2], (double)c0.z, d); d = fma(xn[3], (double)c0.w, d);
        d = fma(xn[4], (double)c1.x, d); d = fma(xn[5], (double)c1.y, d);
        d = fma(xn[6], (double)c1.z, d); d = fma(xn[7], (double)c1.w, d);
        #pragma unroll
        for (int mk = 1; mk < 64; mk <<= 1) d += __shfl_xor(d, mk, 64);
        sc[c] = d / fmax(sqrt(cnorm2[vv[c]]), 1e-12);
    }

    double s1 = -1.0e300, s2 = -1.0e300;
    int bi = 0x7fffffff;
    #pragma unroll
    for (int c = 0; c < 8; c++) {
        if (sc[c] > s1 || (sc[c] == s1 && vv[c] < bi)) {
            s2 = s1;
            s1 = sc[c];
            bi = vv[c];
        } else if (sc[c] > s2) {
            s2 = sc[c];
        }
    }

    if (lane == 0) {
        out[row] = mask[row] ? bi : 0;
        if (s1 - s2 < MARGIN_TAU) {
            u32 pos = atomicAdd(count, 1u);
            wl[pos] = (u32)row;
            u32* cd = cands8 + (size_t)row * 8;
            #pragma unroll
            for (int c = 0; c < 8; c++) cd[c] = (u32)vv[c];
        }
    }
}

// ---------------- kernel 5: exact fp64 fix for flagged rows ----------------
// Exact math identical to the twice-passed version; now 8 candidates.
__global__ __launch_bounds__(256) void k_fix(const float* __restrict__ x,
                                             const float* __restrict__ P,
                                             const float* __restrict__ cb,
                                             const double* __restrict__ cnorm2,
                                             const u32* __restrict__ wl,
                                             const u32* __restrict__ count,
                                             const u32* __restrict__ cands8,
                                             const int* __restrict__ mask,
                                             int* __restrict__ out) {
    const int lane = threadIdx.x & 63;
    const int waveId = blockIdx.x * 4 + (threadIdx.x >> 6);
    const u32 n = *count;

    for (u32 item = waveId; item < n; item += 256) {
        const int row = (int)wl[item];
        const int c0 = lane * 8;

        float xr[8];
        #pragma unroll
        for (int j = 0; j < 8; j++) xr[j] = x[(size_t)row * 512 + c0 + j];

        double yd[8];
        #pragma unroll
        for (int j = 0; j < 8; j++) yd[j] = 0.0;

        for (int k8 = 0; k8 < 64; ++k8) {
            #pragma unroll
            for (int j = 0; j < 8; j++) {
                const double xk = (double)__shfl(xr[j], k8, 64);
                const int k = k8 * 8 + j;
                const float* pr = P + (size_t)k * 512 + c0;
                float4 p0 = *(const float4*)pr;
                float4 p1 = *(const float4*)(pr + 4);
                yd[0] = fma(xk, (double)p0.x, yd[0]);
                yd[1] = fma(xk, (double)p0.y, yd[1]);
                yd[2] = fma(xk, (double)p0.z, yd[2]);
                yd[3] = fma(xk, (double)p0.w, yd[3]);
                yd[4] = fma(xk, (double)p1.x, yd[4]);
                yd[5] = fma(xk, (double)p1.y, yd[5]);
                yd[6] = fma(xk, (double)p1.z, yd[6]);
                yd[7] = fma(xk, (double)p1.w, yd[7]);
            }
        }

        double ss = 0.0;
        #pragma unroll
        for (int e = 0; e < 8; e++) ss = fma(yd[e], yd[e], ss);
        #pragma unroll
        for (int mk = 1; mk < 64; mk <<= 1) ss += __shfl_xor(ss, mk, 64);
        const double xinv = 1.0 / fmax(sqrt(ss), 1e-12);
        double xn[8];
        #pragma unroll
        for (int e = 0; e < 8; e++) xn[e] = yd[e] * xinv;

        double bs = -1.0e300;
        int bi = 0x7fffffff;
        #pragma unroll
        for (int c = 0; c < 8; c++) {
            const int v = (int)cands8[(size_t)row * 8 + c];
            const float* cr = cb + (size_t)v * 512 + c0;
            float4 q0 = *(const float4*)cr;
            float4 q1 = *(const float4*)(cr + 4);
            double d = 0.0;
            d = fma(xn[0], (double)q0.x, d); d = fma(xn[1], (double)q0.y, d);
            d = fma(xn[2], (double)q0.z, d); d = fma(xn[3], (double)q0.w, d);
            d = fma(xn[4], (double)q1.x, d); d = fma(xn[5], (double)q1.y, d);
            d = fma(xn[6], (double)q1.z, d); d = fma(xn[7], (double)q1.w, d);
            #pragma unroll
            for (int mk = 1; mk < 64; mk <<= 1) d += __shfl_xor(d, mk, 64);
            const double s = d / fmax(sqrt(cnorm2[v]), 1e-12);
            if (s > bs || (s == bs && v < bi)) { bs = s; bi = v; }
        }
        if (lane == 0) out[row] = mask[row] ? bi : 0;
    }
}

// ---------------- launcher ----------------
extern "C" void kernel_launch(void* const* d_in, const int* in_sizes, int n_in,
                              void* d_out, int out_size, void* d_ws, size_t ws_size,
                              hipStream_t stream) {
    const float* x = (const float*)d_in[0];               // [32768,512] fp32
    const int* mask = (const int*)d_in[1];                // [32768] bool->int32
    const float* projection = (const float*)d_in[2];      // [512,512] fp32
    const float* codebooks = (const float*)d_in[3];       // [8192,512] fp32
    int* out = (int*)d_out;                               // [32768] int32

    // workspace layout (~76 MB; 86.1 MB proven available).
    // xbf is dead after k_proj -> part2 aliases its 32 MB.
    char* ws = (char*)d_ws;
    ushort_t* xbf  = (ushort_t*)ws;                        // 32 MB [0,32)
    u64* part2     = (u64*)ws;                             // 32 MB (aliases xbf)
    ushort_t* ybf  = (ushort_t*)(ws + (32u << 20));        // 32 MB [32,64)
    ushort_t* cbf  = (ushort_t*)(ws + (64u << 20));        // 8 MB  [64,72)
    ushort_t* pbT  = (ushort_t*)(ws + (72u << 20));        // 512 KB
    double* cnorm2 = (double*)(ws + (73u << 20));          // 64 KB
    u32* cands8    = (u32*)(ws + (74u << 20));             // 1 MB
    u32* wl        = (u32*)(ws + (75u << 20));             // 128 KB
    u32* count     = (u32*)(ws + (76u << 20));             // 4 B

    k_zero<<<1, 64, 0, stream>>>(count);
    k_cvt8<<<2048, 256, 0, stream>>>(x, xbf, 32768 * 512 / 8);
    k_trP<<<dim3(8, 8), 256, 0, stream>>>(projection, pbT);
    k_codes<<<8192, 128, 0, stream>>>(codebooks, cbf, cnorm2);
    k_proj<<<dim3(256, 4), 256, 0, stream>>>(xbf, pbT, ybf);
    k_gemm<<<dim3(256, 64), 256, 0, stream>>>(ybf, cbf, part2);
    k_scorepick<<<8192, 256, 0, stream>>>(part2, ybf, codebooks, cnorm2, mask, out,
                                          wl, count, cands8);
    k_fix<<<64, 256, 0, stream>>>(x, projection, codebooks, cnorm2, wl, count,
                                  cands8, mask, out);
}

// Round 6
// 700.277 us; speedup vs baseline: 1.6643x; 1.6643x over previous
//
#include <hip/hip_runtime.h>
#include <hip/hip_bf16.h>
#include <cstdint>
#include <cstddef>

typedef unsigned long long u64;
typedef unsigned int u32;
typedef unsigned short ushort_t;

typedef __attribute__((ext_vector_type(8))) short short8;
typedef __attribute__((ext_vector_type(4))) float f32x4;

// ---------------- utilities ----------------
__device__ __forceinline__ u64 shfl_xor_u64(u64 v, int m) {
    u32 lo = (u32)v;
    u32 hi = (u32)(v >> 32);
    lo = __shfl_xor(lo, m, 64);
    hi = __shfl_xor(hi, m, 64);
    return ((u64)hi << 32) | lo;
}

__device__ __forceinline__ ushort_t f2bf(float f) {
    u32 u = __float_as_uint(f);
    u32 r = (u + 0x7fffu + ((u >> 16) & 1u)) >> 16;
    return (ushort_t)r;
}

// sorted-insert key k into ascending top-4
__device__ __forceinline__ void ins4(u64& t0, u64& t1, u64& t2, u64& t3, u64 k) {
    bool c0 = k < t0, c1 = k < t1, c2 = k < t2, c3 = k < t3;
    t3 = c3 ? (c2 ? t2 : k) : t3;
    t2 = c2 ? (c1 ? t1 : k) : t2;
    t1 = c1 ? (c0 ? t0 : k) : t1;
    t0 = c0 ? k : t0;
}

__device__ __forceinline__ void butterfly4(u64& t0, u64& t1, u64& t2, u64& t3) {
    #pragma unroll
    for (int mk = 1; mk < 64; mk <<= 1) {
        u64 o0 = shfl_xor_u64(t0, mk), o1 = shfl_xor_u64(t1, mk);
        u64 o2 = shfl_xor_u64(t2, mk), o3 = shfl_xor_u64(t3, mk);
        ins4(t0, t1, t2, t3, o0);
        ins4(t0, t1, t2, t3, o1);
        ins4(t0, t1, t2, t3, o2);
        ins4(t0, t1, t2, t3, o3);
    }
}

// descending merge of sorted float pairs (a1>=a2), (b1>=b2) -> top-2
__device__ __forceinline__ void merge_desc(float& a1, float& a2, float b1, float b2) {
    float lo = fminf(a1, b1);
    a1 = fmaxf(a1, b1);
    a2 = fmaxf(lo, fmaxf(a2, b2));
}

// ---------------- kernel 0: zero the worklist counter ----------------
__global__ void k_zero(u32* __restrict__ count) {
    if (threadIdx.x == 0) *count = 0;
}

// ---------------- kernel A: fp32 -> bf16 elementwise ----------------
__global__ void k_cvt8(const float* __restrict__ src, ushort_t* __restrict__ dst, int n8) {
    int i = blockIdx.x * blockDim.x + threadIdx.x;
    const int stride = gridDim.x * blockDim.x;
    for (; i < n8; i += stride) {
        float4 a = ((const float4*)src)[(size_t)i * 2];
        float4 b = ((const float4*)src)[(size_t)i * 2 + 1];
        short8 p;
        p[0] = (short)f2bf(a.x); p[1] = (short)f2bf(a.y);
        p[2] = (short)f2bf(a.z); p[3] = (short)f2bf(a.w);
        p[4] = (short)f2bf(b.x); p[5] = (short)f2bf(b.y);
        p[6] = (short)f2bf(b.z); p[7] = (short)f2bf(b.w);
        ((short8*)dst)[i] = p;
    }
}

// ---------------- kernel B: transpose P [k][n] -> PT [n][k], bf16 ----------------
__global__ __launch_bounds__(256) void k_trP(const float* __restrict__ P,
                                             ushort_t* __restrict__ PT) {
    __shared__ float t[64][65];
    const int tx = threadIdx.x & 63;
    const int ty = threadIdx.x >> 6;
    const int kb = blockIdx.x * 64;
    const int nb = blockIdx.y * 64;
    #pragma unroll
    for (int r = ty; r < 64; r += 4) t[r][tx] = P[(size_t)(kb + r) * 512 + nb + tx];
    __syncthreads();
    #pragma unroll
    for (int r = ty; r < 64; r += 4)
        PT[(size_t)(nb + r) * 512 + kb + tx] = f2bf(t[tx][r]);
}

// ---------------- kernel 1: normalize codebooks -> bf16 ----------------
__global__ void k_codes(const float* __restrict__ cb, ushort_t* __restrict__ cbf) {
    const int row = blockIdx.x;
    const int t = threadIdx.x;
    const float* src = cb + (size_t)row * 512 + t * 4;
    float4 v = *(const float4*)src;
    double s = (double)v.x * v.x + (double)v.y * v.y + (double)v.z * v.z + (double)v.w * v.w;
    #pragma unroll
    for (int m = 1; m < 64; m <<= 1) s += __shfl_xor(s, m, 64);
    __shared__ double sw[2];
    if ((t & 63) == 0) sw[t >> 6] = s;
    __syncthreads();
    double tot = sw[0] + sw[1];
    double inv = 1.0 / fmax(sqrt(tot), 1e-12);
    ushort4 o;
    o.x = f2bf((float)((double)v.x * inv));
    o.y = f2bf((float)((double)v.y * inv));
    o.z = f2bf((float)((double)v.z * inv));
    o.w = f2bf((float)((double)v.w * inv));
    *(ushort4*)(cbf + (size_t)row * 512 + t * 4) = o;
}

// ---------------- kernel 2: projection GEMM ybf = xbf @ PT^T via MFMA ----------------
__global__ __launch_bounds__(256) void k_proj(const ushort_t* __restrict__ X,
                                              const ushort_t* __restrict__ PT,
                                              ushort_t* __restrict__ Ybf) {
    __shared__ ushort_t Ab[128 * 64];
    __shared__ ushort_t Bb[128 * 64];
    const int tid = threadIdx.x;
    const int lane = tid & 63;
    const int wid = tid >> 6;
    const int wm = wid & 1, wn = wid >> 1;
    const int rowBase = blockIdx.x * 128;
    const int colBase = blockIdx.y * 128;

    const ushort_t* asrc[4];
    const ushort_t* bsrc[4];
    int ldsoff[4];
    #pragma unroll
    for (int i = 0; i < 4; i++) {
        const int L = i * 256 + tid;
        const int r = L >> 3;
        const int s = (L & 7) ^ (r & 7);
        asrc[i] = X + (size_t)(rowBase + r) * 512 + s * 8;
        bsrc[i] = PT + (size_t)(colBase + r) * 512 + s * 8;
        ldsoff[i] = (i * 256 + (tid & ~63)) * 16;
    }

    f32x4 acc[4][4];
    #pragma unroll
    for (int i = 0; i < 4; i++)
        #pragma unroll
        for (int j = 0; j < 4; j++) {
            f32x4 z = {0.f, 0.f, 0.f, 0.f};
            acc[i][j] = z;
        }

    int aoff[4][2], boff[4][2];
    #pragma unroll
    for (int ti = 0; ti < 4; ti++)
        #pragma unroll
        for (int ks = 0; ks < 2; ks++) {
            const int sa = ks * 4 + (lane >> 4);
            const int ra = wm * 64 + ti * 16 + (lane & 15);
            aoff[ti][ks] = (ra * 8 + (sa ^ (ra & 7))) * 8;
            const int rb = wn * 64 + ti * 16 + (lane & 15);
            boff[ti][ks] = (rb * 8 + (sa ^ (rb & 7))) * 8;
        }

    for (int kt = 0; kt < 512; kt += 64) {
        #pragma unroll
        for (int i = 0; i < 4; i++) {
            __builtin_amdgcn_global_load_lds(
                (const __attribute__((address_space(1))) uint32_t*)(asrc[i] + kt),
                (__attribute__((address_space(3))) uint32_t*)((char*)Ab + ldsoff[i]), 16, 0, 0);
            __builtin_amdgcn_global_load_lds(
                (const __attribute__((address_space(1))) uint32_t*)(bsrc[i] + kt),
                (__attribute__((address_space(3))) uint32_t*)((char*)Bb + ldsoff[i]), 16, 0, 0);
        }
        __syncthreads();
        short8 af[4][2], bfr[4][2];
        #pragma unroll
        for (int ti = 0; ti < 4; ti++)
            #pragma unroll
            for (int ks = 0; ks < 2; ks++) {
                af[ti][ks]  = *(const short8*)(Ab + aoff[ti][ks]);
                bfr[ti][ks] = *(const short8*)(Bb + boff[ti][ks]);
            }
        #pragma unroll
        for (int ks = 0; ks < 2; ks++)
            #pragma unroll
            for (int ti = 0; ti < 4; ti++)
                #pragma unroll
                for (int tj = 0; tj < 4; tj++)
                    acc[ti][tj] = __builtin_amdgcn_mfma_f32_16x16x32_bf16(
                        af[ti][ks], bfr[tj][ks], acc[ti][tj], 0, 0, 0);
        __syncthreads();
    }

    #pragma unroll
    for (int ti = 0; ti < 4; ti++)
        #pragma unroll
        for (int tj = 0; tj < 4; tj++) {
            const int col = colBase + wn * 64 + tj * 16 + (lane & 15);
            #pragma unroll
            for (int reg = 0; reg < 4; reg++) {
                const int row = rowBase + wm * 64 + ti * 16 + (lane >> 4) * 4 + reg;
                Ybf[(size_t)row * 512 + col] = f2bf(acc[ti][tj][reg]);
            }
        }
}

// ---------------- kernel 3: bf16 MFMA GEMM, embedded-index float top-2 epilogue ----------------
// grid (256, 64). acc init = 16.0 (score offset, keeps keys positive). Low 7 mantissa
// bits of each score carry (127 - col_within_block); fmax ties then prefer smaller col.
// part2[row][64 blocks][2] u32 (float bits of block top-2).
__global__ __launch_bounds__(256) void k_gemm(const ushort_t* __restrict__ Y,
                                              const ushort_t* __restrict__ C,
                                              u32* __restrict__ part2) {
    __shared__ ushort_t Ab[128 * 64];
    __shared__ ushort_t Bb[128 * 64];
    __shared__ u32 tmp[128][2][2][2];   // [row][wn][grp][2]
    const int tid = threadIdx.x;
    const int lane = tid & 63;
    const int wid = tid >> 6;
    const int wm = wid & 1, wn = wid >> 1;
    const int rowBase = blockIdx.x * 128;
    const int colBase = blockIdx.y * 128;

    const ushort_t* asrc[4];
    const ushort_t* bsrc[4];
    int ldsoff[4];
    #pragma unroll
    for (int i = 0; i < 4; i++) {
        const int L = i * 256 + tid;
        const int r = L >> 3;
        const int s = (L & 7) ^ (r & 7);
        asrc[i] = Y + (size_t)(rowBase + r) * 512 + s * 8;
        bsrc[i] = C + (size_t)(colBase + r) * 512 + s * 8;
        ldsoff[i] = (i * 256 + (tid & ~63)) * 16;
    }

    f32x4 acc[4][4];
    #pragma unroll
    for (int i = 0; i < 4; i++)
        #pragma unroll
        for (int j = 0; j < 4; j++) {
            f32x4 z = {16.f, 16.f, 16.f, 16.f};
            acc[i][j] = z;
        }

    int aoff[4][2], boff[4][2];
    #pragma unroll
    for (int ti = 0; ti < 4; ti++)
        #pragma unroll
        for (int ks = 0; ks < 2; ks++) {
            const int sa = ks * 4 + (lane >> 4);
            const int ra = wm * 64 + ti * 16 + (lane & 15);
            aoff[ti][ks] = (ra * 8 + (sa ^ (ra & 7))) * 8;
            const int rb = wn * 64 + ti * 16 + (lane & 15);
            boff[ti][ks] = (rb * 8 + (sa ^ (rb & 7))) * 8;
        }

    // embedded col ids: 127 - (wn*64 + tj*16 + (lane&15))
    u32 ecol[4];
    #pragma unroll
    for (int tj = 0; tj < 4; tj++) ecol[tj] = 127u - (u32)(wn * 64 + tj * 16 + (lane & 15));

    for (int kt = 0; kt < 512; kt += 64) {
        #pragma unroll
        for (int i = 0; i < 4; i++) {
            __builtin_amdgcn_global_load_lds(
                (const __attribute__((address_space(1))) uint32_t*)(asrc[i] + kt),
                (__attribute__((address_space(3))) uint32_t*)((char*)Ab + ldsoff[i]), 16, 0, 0);
            __builtin_amdgcn_global_load_lds(
                (const __attribute__((address_space(1))) uint32_t*)(bsrc[i] + kt),
                (__attribute__((address_space(3))) uint32_t*)((char*)Bb + ldsoff[i]), 16, 0, 0);
        }
        __syncthreads();
        short8 af[4][2], bfr[4][2];
        #pragma unroll
        for (int ti = 0; ti < 4; ti++)
            #pragma unroll
            for (int ks = 0; ks < 2; ks++) {
                af[ti][ks]  = *(const short8*)(Ab + aoff[ti][ks]);
                bfr[ti][ks] = *(const short8*)(Bb + boff[ti][ks]);
            }
        #pragma unroll
        for (int ks = 0; ks < 2; ks++)
            #pragma unroll
            for (int ti = 0; ti < 4; ti++)
                #pragma unroll
                for (int tj = 0; tj < 4; tj++)
                    acc[ti][tj] = __builtin_amdgcn_mfma_f32_16x16x32_bf16(
                        af[ti][ks], bfr[tj][ks], acc[ti][tj], 0, 0, 0);
        __syncthreads();
    }

    // epilogue: embed col, per-thread top-2 of 4 cols, 3-step butterfly (8-lane groups)
    #pragma unroll
    for (int ti = 0; ti < 4; ti++)
        #pragma unroll
        for (int reg = 0; reg < 4; reg++) {
            float v0 = __uint_as_float((__float_as_uint(acc[ti][0][reg]) & 0xFFFFFF80u) | ecol[0]);
            float v1 = __uint_as_float((__float_as_uint(acc[ti][1][reg]) & 0xFFFFFF80u) | ecol[1]);
            float v2 = __uint_as_float((__float_as_uint(acc[ti][2][reg]) & 0xFFFFFF80u) | ecol[2]);
            float v3 = __uint_as_float((__float_as_uint(acc[ti][3][reg]) & 0xFFFFFF80u) | ecol[3]);
            float m1 = fmaxf(v0, v1);
            float m2 = fminf(v0, v1);
            float med = __builtin_amdgcn_fmed3f(m1, v2, v3);
            m1 = fmaxf(m1, fmaxf(v2, v3));
            m2 = fmaxf(m2, med);
            #pragma unroll
            for (int mk = 1; mk < 8; mk <<= 1) {
                float o1 = __shfl_xor(m1, mk, 64);
                float o2 = __shfl_xor(m2, mk, 64);
                merge_desc(m1, m2, o1, o2);
            }
            if ((lane & 7) == 0) {
                const int mrow = wm * 64 + ti * 16 + (lane >> 4) * 4 + reg;
                const int grp = (lane >> 3) & 1;
                tmp[mrow][wn][grp][0] = __float_as_uint(m1);
                tmp[mrow][wn][grp][1] = __float_as_uint(m2);
            }
        }
    __syncthreads();
    if (tid < 128) {
        float a1 = __uint_as_float(tmp[tid][0][0][0]), a2 = __uint_as_float(tmp[tid][0][0][1]);
        merge_desc(a1, a2, __uint_as_float(tmp[tid][0][1][0]), __uint_as_float(tmp[tid][0][1][1]));
        merge_desc(a1, a2, __uint_as_float(tmp[tid][1][0][0]), __uint_as_float(tmp[tid][1][0][1]));
        merge_desc(a1, a2, __uint_as_float(tmp[tid][1][1][0]), __uint_as_float(tmp[tid][1][1][1]));
        u32* dst = part2 + ((size_t)(rowBase + tid) * 64 + blockIdx.y) * 2;
        dst[0] = __float_as_uint(a1);
        dst[1] = __float_as_uint(a2);
    }
}

// ---------------- kernel 4: merge keys -> winner; flag near-ties -> worklist ----------------
// grid 8192 x 256 (wave per row). Reads 128 u32 keys/row; no codebook access.
__global__ __launch_bounds__(256) void k_pick(const u32* __restrict__ part2,
                                              const int* __restrict__ mask,
                                              int* __restrict__ out,
                                              u32* __restrict__ wl,
                                              u32* __restrict__ count,
                                              u32* __restrict__ cands8) {
    const int row = blockIdx.x * 4 + (threadIdx.x >> 6);
    const int lane = threadIdx.x & 63;
    const u32* base = part2 + (size_t)row * 128;

    const u32 b0 = base[lane];
    const u32 b1 = base[64 + lane];
    // rebuild exact-sortable u64 keys with global col
    const u32 sc0 = b0 & 0xFFFFFF80u;
    const u32 sc1 = b1 & 0xFFFFFF80u;
    const u32 col0 = (u32)(lane >> 1) * 128u + (127u - (b0 & 0x7Fu));
    const u32 col1 = (u32)((64 + lane) >> 1) * 128u + (127u - (b1 & 0x7Fu));
    const u64 k0 = ((u64)(~sc0) << 13) | col0;
    const u64 k1 = ((u64)(~sc1) << 13) | col1;

    // pass 1: global top-4
    u64 t0 = k0 < k1 ? k0 : k1;
    u64 t1 = k0 < k1 ? k1 : k0;
    u64 t2 = ~0ull, t3 = ~0ull;
    butterfly4(t0, t1, t2, t3);
    const u64 g0 = t0, g1 = t1, g2 = t2, g3 = t3;

    // pass 2: next-4 (keys are globally unique per row)
    u64 e0 = (k0 == g0 || k0 == g1 || k0 == g2 || k0 == g3) ? ~0ull : k0;
    u64 e1 = (k1 == g0 || k1 == g1 || k1 == g2 || k1 == g3) ? ~0ull : k1;
    u64 u0 = e0 < e1 ? e0 : e1;
    u64 u1 = e0 < e1 ? e1 : e0;
    u64 u2 = ~0ull, u3 = ~0ull;
    butterfly4(u0, u1, u2, u3);

    if (lane == 0) {
        const float s1 = __uint_as_float(~(u32)(g0 >> 13)) - 16.0f;
        const float s2 = __uint_as_float(~(u32)(g1 >> 13)) - 16.0f;
        const int c1 = (int)(g0 & 0x1FFFu);
        out[row] = mask[row] ? c1 : 0;
        if (s1 - s2 < 0.006f * fabsf(s1) + 0.002f) {
            u32 pos = atomicAdd(count, 1u);
            wl[pos] = (u32)row;
            u32* cd = cands8 + (size_t)row * 8;
            cd[0] = (u32)(g0 & 0x1FFFu); cd[1] = (u32)(g1 & 0x1FFFu);
            cd[2] = (u32)(g2 & 0x1FFFu); cd[3] = (u32)(g3 & 0x1FFFu);
            cd[4] = (u32)(u0 & 0x1FFFu); cd[5] = (u32)(u1 & 0x1FFFu);
            cd[6] = (u32)(u2 & 0x1FFFu); cd[7] = (u32)(u3 & 0x1FFFu);
        }
    }
}

// ---------------- kernel 5: exact fp64 fix (round-2-proven math), worklist-driven ----------------
// 16 rows/block staged in LDS, P streamed once per block. grid-stride over worklist.
__global__ __launch_bounds__(256) void k_fix16(const float* __restrict__ x,
                                               const float* __restrict__ P,
                                               const float* __restrict__ cb,
                                               const u32* __restrict__ wl,
                                               const u32* __restrict__ count,
                                               const u32* __restrict__ cands8,
                                               const int* __restrict__ mask,
                                               int* __restrict__ out) {
    __shared__ float xs[16][512];
    __shared__ u32 cands_s[16][8];
    __shared__ double nrmw[4][16];
    __shared__ double invn[16];
    __shared__ double wredD[4][8];
    __shared__ double wredC[4][8];
    __shared__ int bestIdx[16];
    const int tid = threadIdx.x;
    const u32 n = *count;

    for (u32 basei = (u32)blockIdx.x * 16u; basei < n; basei += (u32)gridDim.x * 16u) {
        const int nr = (int)((n - basei < 16u) ? (n - basei) : 16u);
        __syncthreads();

        // stage 16 (clamped) x rows + candidate lists
        {
            const int r = tid >> 4;
            const int rc = r < nr ? r : nr - 1;
            const u32 ridx = wl[basei + rc];
            const float4* src = (const float4*)(x + (size_t)ridx * 512);
            float4* dst = (float4*)&xs[r][0];
            const int c = tid & 15;
            #pragma unroll
            for (int j = 0; j < 8; j++) dst[c + j * 16] = src[c + j * 16];
        }
        if (tid < 16 * 8) {
            const int rr = tid >> 3;
            const int rc = rr < nr ? rr : nr - 1;
            cands_s[rr][tid & 7] = cands8[(size_t)wl[basei + rc] * 8 + (tid & 7)];
        }
        __syncthreads();

        // fp64 projection: thread owns columns d0, d0+1 for all 16 rows
        const int d0 = tid * 2;
        double acc[16][2];
        #pragma unroll
        for (int r = 0; r < 16; r++) { acc[r][0] = 0.0; acc[r][1] = 0.0; }
        const float* pp = P + d0;
        for (int k = 0; k < 512; k += 2) {
            float2 pa = *(const float2*)(pp + (size_t)k * 512);
            float2 pb = *(const float2*)(pp + (size_t)(k + 1) * 512);
            const double pa0 = (double)pa.x, pa1 = (double)pa.y;
            const double pb0 = (double)pb.x, pb1 = (double)pb.y;
            #pragma unroll
            for (int r = 0; r < 16; r++) {
                float2 xv = *(const float2*)&xs[r][k];
                const double x0 = (double)xv.x, x1 = (double)xv.y;
                acc[r][0] = fma(x0, pa0, acc[r][0]);
                acc[r][1] = fma(x0, pa1, acc[r][1]);
                acc[r][0] = fma(x1, pb0, acc[r][0]);
                acc[r][1] = fma(x1, pb1, acc[r][1]);
            }
        }

        // fp64 row norms
        #pragma unroll
        for (int r = 0; r < 16; r++) {
            double s = fma(acc[r][0], acc[r][0], acc[r][1] * acc[r][1]);
            #pragma unroll
            for (int mk = 1; mk < 64; mk <<= 1) s += __shfl_xor(s, mk, 64);
            if ((tid & 63) == 0) nrmw[tid >> 6][r] = s;
        }
        __syncthreads();
        if (tid < 16) {
            double t = nrmw[0][tid] + nrmw[1][tid] + nrmw[2][tid] + nrmw[3][tid];
            invn[tid] = 1.0 / fmax(sqrt(t), 1e-12);
        }
        __syncthreads();

        // rescore the 8 candidates per row in fp64 from raw codebooks
        for (int r = 0; r < nr; r++) {
            const double xinv = invn[r];
            const double xn0 = acc[r][0] * xinv;
            const double xn1 = acc[r][1] * xinv;
            int vidx[8];
            double pd[8], pc[8];
            #pragma unroll
            for (int c = 0; c < 8; c++) {
                vidx[c] = (int)cands_s[r][c];
                float2 cv = *(const float2*)(cb + (size_t)vidx[c] * 512 + d0);
                const double c0 = (double)cv.x, c1 = (double)cv.y;
                pd[c] = fma(c0, xn0, c1 * xn1);
                pc[c] = fma(c0, c0, c1 * c1);
            }
            #pragma unroll
            for (int mk = 1; mk < 64; mk <<= 1) {
                #pragma unroll
                for (int c = 0; c < 8; c++) {
                    pd[c] += __shfl_xor(pd[c], mk, 64);
                    pc[c] += __shfl_xor(pc[c], mk, 64);
                }
            }
            if ((tid & 63) == 0) {
                const int w = tid >> 6;
                #pragma unroll
                for (int c = 0; c < 8; c++) { wredD[w][c] = pd[c]; wredC[w][c] = pc[c]; }
            }
            __syncthreads();
            if (tid == 0) {
                double bs = -1.0e300;
                int bi = 0x7fffffff;
                #pragma unroll
                for (int c = 0; c < 8; c++) {
                    const double D = wredD[0][c] + wredD[1][c] + wredD[2][c] + wredD[3][c];
                    const double Cw = wredC[0][c] + wredC[1][c] + wredC[2][c] + wredC[3][c];
                    const double s = D / fmax(sqrt(Cw), 1e-12);
                    const int v = vidx[c];
                    if (s > bs || (s == bs && v < bi)) { bs = s; bi = v; }
                }
                bestIdx[r] = bi;
            }
            __syncthreads();
        }

        if (tid < nr) {
            const u32 row = wl[basei + tid];
            out[row] = mask[row] ? bestIdx[tid] : 0;
        }
    }
}

// ---------------- launcher ----------------
extern "C" void kernel_launch(void* const* d_in, const int* in_sizes, int n_in,
                              void* d_out, int out_size, void* d_ws, size_t ws_size,
                              hipStream_t stream) {
    const float* x = (const float*)d_in[0];               // [32768,512] fp32
    const int* mask = (const int*)d_in[1];                // [32768] bool->int32
    const float* projection = (const float*)d_in[2];      // [512,512] fp32
    const float* codebooks = (const float*)d_in[3];       // [8192,512] fp32
    int* out = (int*)d_out;                               // [32768] int32

    // workspace (~76 MB): xbf dead after k_proj -> part2 aliases it.
    char* ws = (char*)d_ws;
    ushort_t* xbf = (ushort_t*)ws;                         // 32 MB [0,32)
    u32* part2    = (u32*)ws;                              // 16 MB (aliases xbf)
    ushort_t* ybf = (ushort_t*)(ws + (32u << 20));         // 32 MB [32,64)
    ushort_t* cbf = (ushort_t*)(ws + (64u << 20));         // 8 MB  [64,72)
    ushort_t* pbT = (ushort_t*)(ws + (72u << 20));         // 512 KB
    u32* cands8   = (u32*)(ws + (73u << 20));              // 1 MB
    u32* wl       = (u32*)(ws + (74u << 20));              // 128 KB
    u32* count    = (u32*)(ws + (75u << 20));              // 4 B

    k_zero<<<1, 64, 0, stream>>>(count);
    k_cvt8<<<2048, 256, 0, stream>>>(x, xbf, 32768 * 512 / 8);
    k_trP<<<dim3(8, 8), 256, 0, stream>>>(projection, pbT);
    k_codes<<<8192, 128, 0, stream>>>(codebooks, cbf);
    k_proj<<<dim3(256, 4), 256, 0, stream>>>(xbf, pbT, ybf);
    k_gemm<<<dim3(256, 64), 256, 0, stream>>>(ybf, cbf, part2);
    k_pick<<<8192, 256, 0, stream>>>(part2, mask, out, wl, count, cands8);
    k_fix16<<<256, 256, 0, stream>>>(x, projection, codebooks, wl, count,
                                     cands8, mask, out);
}